// Round 1
// baseline (389.457 us; speedup 1.0000x reference)
//
#include <hip/hip_runtime.h>
#include <math.h>

#define DIM 256
#define OUT 8
#define EPS 1e-5f

// One thread per token. Weights (W1/W2/b1/b2/gamma/beta) are accessed with
// wave-uniform indices -> compiler emits scalar (s_load) accesses, leaving the
// vector memory pipe entirely for streaming x.
__global__ __launch_bounds__(256) void ffn_kernel(
    const float* __restrict__ x,
    const float* __restrict__ W1,
    const float* __restrict__ b1,
    const float* __restrict__ W2,
    const float* __restrict__ b2,
    const float* __restrict__ gamma,
    const float* __restrict__ beta,
    float* __restrict__ out,
    int n_tokens)
{
    int t = blockIdx.x * blockDim.x + threadIdx.x;
    if (t >= n_tokens) return;

    const float4* xv  = (const float4*)(x + (size_t)t * DIM);
    const float4* w1v = (const float4*)W1;

    float acc[OUT];
    #pragma unroll
    for (int o = 0; o < OUT; ++o) acc[o] = b1[o];

    // unroll 4: each thread consumes a full 64B line per unrolled cluster,
    // so divergent 16B/lane loads reuse their cache line immediately.
    #pragma unroll 4
    for (int j = 0; j < DIM/4; ++j) {
        float4 xj = xv[j];
        #pragma unroll
        for (int o = 0; o < OUT; ++o) {
            float4 w = w1v[o*(DIM/4) + j];   // wave-uniform -> s_load
            acc[o] = fmaf(xj.x, w.x, acc[o]);
            acc[o] = fmaf(xj.y, w.y, acc[o]);
            acc[o] = fmaf(xj.z, w.z, acc[o]);
            acc[o] = fmaf(xj.w, w.w, acc[o]);
        }
    }

    // exact GELU (erf), matches jax.nn.gelu(approximate=False)
    float g[OUT];
    #pragma unroll
    for (int o = 0; o < OUT; ++o) {
        float h = acc[o];
        g[o] = 0.5f * h * (1.0f + erff(h * 0.70710678118654752f));
    }

    // second linear (8x8) — W2 wave-uniform -> s_load
    float h2[OUT];
    float sum = 0.f;
    #pragma unroll
    for (int p = 0; p < OUT; ++p) {
        float a = b2[p];
        #pragma unroll
        for (int o = 0; o < OUT; ++o)
            a = fmaf(W2[p*OUT + o], g[o], a);
        h2[p] = a;
        sum += a;
    }

    // LayerNorm over OUT=8
    float mu = sum * (1.0f / OUT);
    float vs = 0.f;
    #pragma unroll
    for (int p = 0; p < OUT; ++p) {
        float d = h2[p] - mu;
        vs = fmaf(d, d, vs);
    }
    float rs = rsqrtf(vs * (1.0f / OUT) + EPS);

    float r[OUT];
    #pragma unroll
    for (int p = 0; p < OUT; ++p)
        r[p] = (h2[p] - mu) * rs * gamma[p] + beta[p];

    float4* outv = (float4*)(out + (size_t)t * OUT);
    outv[0] = make_float4(r[0], r[1], r[2], r[3]);
    outv[1] = make_float4(r[4], r[5], r[6], r[7]);
}

extern "C" void kernel_launch(void* const* d_in, const int* in_sizes, int n_in,
                              void* d_out, int out_size, void* d_ws, size_t ws_size,
                              hipStream_t stream) {
    const float* x     = (const float*)d_in[0];
    const float* W1    = (const float*)d_in[1];
    const float* b1    = (const float*)d_in[2];
    const float* W2    = (const float*)d_in[3];
    const float* b2    = (const float*)d_in[4];
    const float* gamma = (const float*)d_in[5];
    const float* beta  = (const float*)d_in[6];
    float* out = (float*)d_out;

    int n_tokens = in_sizes[0] / DIM;          // 262144
    int block = 256;
    int grid = (n_tokens + block - 1) / block; // 1024
    ffn_kernel<<<grid, block, 0, stream>>>(x, W1, b1, W2, b2, gamma, beta, out, n_tokens);
}